// Round 7
// baseline (85.790 us; speedup 1.0000x reference)
//
#include <hip/hip_runtime.h>

// Problem constants (from reference: img_feats (8, 2048, 256) fp32)
#define BATCH 8
#define SEQ   2048
#define DIM   256
#define TINV  10.0f   // 1 / TEMPERATURE
#define NEGW  10      // NEG_WINDOW

#define BMROWS 64                 // rows per block
#define NSTRIP (SEQ / BMROWS)     // 32 strips
// grid = NSTRIP*BATCH = 256 blocks; blockIdx.x = strip*8 + batch so the
// natural %8 XCD round-robin keeps each batch's 1MB slice in one XCD L2.

typedef float f32x4  __attribute__((ext_vector_type(4)));
typedef short bf16x8 __attribute__((ext_vector_type(8)));

// float -> bf16 (round-to-nearest-even), bf16 bits -> float
__device__ __forceinline__ unsigned short f2b(float f) {
  union { float f; unsigned u; } v; v.f = f;
  unsigned r = v.u + 0x7fffu + ((v.u >> 16) & 1u);
  return (unsigned short)(r >> 16);
}

// ---------------------------------------------------------------------------
// Kernel 1: L2-normalize rows (fp32 in) -> bf16 normalized rows in workspace.
// Block 64 also zero-inits the loss accumulator + ticket (negsum no longer
// needs init: round-7 sim writes it with plain stores, exclusive owner).
// ---------------------------------------------------------------------------
__global__ void normalize_bf16_kernel(const float* __restrict__ x,
                                      unsigned short* __restrict__ xb,
                                      float* __restrict__ zero_region) {
  if (blockIdx.x == 64 && threadIdx.x < 16) {
    zero_region[16384 + threadIdx.x] = 0.f;   // loss, ticket, pad
  }
  int row  = blockIdx.x * 4 + (threadIdx.x >> 6);
  int lane = threadIdx.x & 63;
  const float4 v = reinterpret_cast<const float4*>(x + (size_t)row * DIM)[lane];
  float ss = v.x * v.x + v.y * v.y + v.z * v.z + v.w * v.w;
#pragma unroll
  for (int off = 32; off; off >>= 1) ss += __shfl_xor(ss, off, 64);
  float rn = 1.0f / fmaxf(sqrtf(ss), 1e-12f);
  ushort4 o;
  o.x = f2b(v.x * rn); o.y = f2b(v.y * rn);
  o.z = f2b(v.z * rn); o.w = f2b(v.w * rn);
  reinterpret_cast<ushort4*>(xb + (size_t)row * DIM)[lane] = o;
}

// ---------------------------------------------------------------------------
// Kernel 2 (round-7 rewrite): one block per (batch, 64-row strip).
// 8 waves = 2 row-halves (mw) x 4 col-quarters (nw). Per wave:
//   - A-frags for its 32 rows, all K: 16 strided 16B loads -> 64 VGPRs, ONCE.
//   - stream 512 cols in 4 nb-chunks of 128; per kc-step prefetch the next
//     step's 8 B-frags into the alternate register buffer (b0/b1, static
//     parity) BEFORE the 16 MFMAs -> loads stay in flight under MFMA.
//   - epilogue per nb: exp+band-mask -> rowpart (regs), sp plain store.
// Block-level: rowpart -> shfl reduce over cl -> LDS atomicAdd -> plain
// negsum store. No global atomics, no barriers in the main loop.
// ---------------------------------------------------------------------------
__global__ __launch_bounds__(512, 2)
void sim_negsum_kernel(const unsigned short* __restrict__ xb,
                       float* __restrict__ negsum,
                       float* __restrict__ sp_out) {
  const int batch = blockIdx.x & 7;
  const int strip = blockIdx.x >> 3;
  const int r0 = strip * BMROWS;

  const int tid  = threadIdx.x;
  const int wid  = tid >> 6;
  const int lane = tid & 63;
  const int mw   = wid >> 2;      // 0..1: rows r0+mw*32 .. +32
  const int nw   = wid & 3;       // 0..3: cols nw*512 .. +512
  const int kg   = lane >> 4;     // 0..3
  const int cl   = lane & 15;

  __shared__ float red[BMROWS];
  if (tid < BMROWS) red[tid] = 0.f;

  const unsigned short* Xb = xb + (size_t)batch * SEQ * DIM;

  // ---- A fragments in registers: rows r0+mw*32+m*16+cl, k = kc*32+kg*8 ----
  bf16x8 af[2][8];
  {
    const unsigned short* Ab = Xb + (size_t)(r0 + mw * 32 + cl) * DIM + kg * 8;
#pragma unroll
    for (int m = 0; m < 2; ++m)
#pragma unroll
      for (int kc = 0; kc < 8; ++kc)
        af[m][kc] = *reinterpret_cast<const bf16x8*>(Ab + m * 16 * DIM + kc * 32);
  }

  // per-lane B base: col nw*512+cl, k-offset kg*8
  const unsigned short* Bb = Xb + (size_t)(nw * 512 + cl) * DIM + kg * 8;

  float rowpart[2][4];
#pragma unroll
  for (int m = 0; m < 2; ++m)
#pragma unroll
    for (int r = 0; r < 4; ++r) rowpart[m][r] = 0.f;

  bf16x8 b0[8], b1[8];
  // preload (nb=0, kc=0) into b0
#pragma unroll
  for (int n = 0; n < 8; ++n)
    b0[n] = *reinterpret_cast<const bf16x8*>(Bb + (size_t)(n * 16) * DIM);

#define LOADB(dst, base)                                                      \
  _Pragma("unroll")                                                           \
  for (int n = 0; n < 8; ++n)                                                 \
    dst[n] = *reinterpret_cast<const bf16x8*>((base) + (size_t)(n * 16) * DIM);

#define MFMAB(cur, kc)                                                        \
  _Pragma("unroll")                                                           \
  for (int m = 0; m < 2; ++m)                                                 \
    _Pragma("unroll")                                                         \
    for (int n = 0; n < 8; ++n)                                               \
      acc[m][n] = __builtin_amdgcn_mfma_f32_16x16x32_bf16(                    \
          af[m][kc], cur[n], acc[m][n], 0, 0, 0);

  for (int nb = 0; nb < 4; ++nb) {
    const unsigned short* Bnb = Bb + (size_t)(nb * 128) * DIM;
    f32x4 acc[2][8];
#pragma unroll
    for (int m = 0; m < 2; ++m)
#pragma unroll
      for (int n = 0; n < 8; ++n)
        acc[m][n] = (f32x4){0.f, 0.f, 0.f, 0.f};

#pragma unroll
    for (int kc = 0; kc < 8; ++kc) {
      if ((kc & 1) == 0) {
        // prefetch next step into b1, consume b0
        LOADB(b1, Bnb + (kc + 1) * 32);
        MFMAB(b0, kc);
      } else if (kc < 7) {
        LOADB(b0, Bnb + (kc + 1) * 32);
        MFMAB(b1, kc);
      } else {
        // kc == 7: prefetch next nb's kc=0 into b0 (hidden under epilogue)
        if (nb < 3) { LOADB(b0, Bb + (size_t)((nb + 1) * 128) * DIM); }
        MFMAB(b1, kc);
      }
    }

    // ---- epilogue for this nb: exp + band mask + rowpart + sp ----
    // C/D layout (HW-verified): col = cl, row_in_tile = kg*4 + rr
#pragma unroll
    for (int m = 0; m < 2; ++m) {
      const int rowb = r0 + mw * 32 + m * 16 + (kg << 2);
#pragma unroll
      for (int n = 0; n < 8; ++n) {
        const int tcol = nw * 512 + nb * 128 + n * 16 + cl;
#pragma unroll
        for (int rr = 0; rr < 4; ++rr) {
          int srow = rowb + rr;
          int diff = tcol - srow;
          int d = diff < 0 ? -diff : diff;
          float sv = acc[m][n][rr] * TINV;
          float e = (d >= NEGW) ? __expf(sv) : 0.f;
          rowpart[m][rr] += e;
          if (diff == 1)   // positive pair (srow, srow+1): unique writer
            sp_out[(size_t)batch * (SEQ - 1) + srow] = sv;
        }
      }
    }
  }
#undef LOADB
#undef MFMAB

  // ---- reduce rowpart over the 16 cl-lanes of each kg group ----
#pragma unroll
  for (int off = 1; off <= 8; off <<= 1)
#pragma unroll
    for (int m = 0; m < 2; ++m)
#pragma unroll
      for (int r = 0; r < 4; ++r)
        rowpart[m][r] += __shfl_xor(rowpart[m][r], off, 64);

  __syncthreads();   // red[] init visible
  if (cl == 0) {
#pragma unroll
    for (int m = 0; m < 2; ++m)
#pragma unroll
      for (int r = 0; r < 4; ++r)
        atomicAdd(&red[mw * 32 + m * 16 + (kg << 2) + r], rowpart[m][r]);
  }
  __syncthreads();
  if (tid < BMROWS)
    negsum[(size_t)batch * SEQ + r0 + tid] = red[tid];
}

// ---------------------------------------------------------------------------
// Kernel 3: positive-pair loss from precomputed sp + FUSED finalize via
// last-block ticket. Every block computes n_valid redundantly; the block
// taking the last ticket reads the final loss and writes out.
// ---------------------------------------------------------------------------
__device__ __forceinline__ int negcnt(int s) {
  int a = s - (NEGW - 1);      if (a < 0) a = 0;
  int b = SEQ - NEGW - s;      if (b < 0) b = 0;
  return a + b;
}

#define POSFIN_BLOCKS 64

__global__ __launch_bounds__(256)
void pos_fin_kernel(const float* __restrict__ sp,
                    const float* __restrict__ negsum,
                    float* __restrict__ loss,
                    unsigned int* __restrict__ ticket,
                    float* __restrict__ out) {
  __shared__ float red[4];
  __shared__ int   nvr[4];
  const int NP = BATCH * (SEQ - 1);
  int pidx = blockIdx.x * 256 + threadIdx.x;
  float term = 0.f;
  if (pidx < NP) {
    int b = pidx / (SEQ - 1), s = pidx % (SEQ - 1);
    float spv = sp[pidx];
    float e = __expf(spv);
    if (negcnt(s) > 0)     term += logf(e + negsum[(size_t)b * SEQ + s])     - spv;
    if (negcnt(s + 1) > 0) term += logf(e + negsum[(size_t)b * SEQ + s + 1]) - spv;
  }
  // n_valid (per-anchor positive counts over valid anchors), generic form
  int cnt = 0;
#pragma unroll
  for (int s = threadIdx.x; s < SEQ; s += 256)
    if (negcnt(s) > 0) cnt += (s > 0) + (s < SEQ - 1);

#pragma unroll
  for (int off = 32; off; off >>= 1) {
    term += __shfl_xor(term, off, 64);
    cnt  += __shfl_xor(cnt,  off, 64);
  }
  if ((threadIdx.x & 63) == 0) {
    red[threadIdx.x >> 6] = term;
    nvr[threadIdx.x >> 6] = cnt;
  }
  __syncthreads();
  if (threadIdx.x == 0) {
    atomicAdd(loss, red[0] + red[1] + red[2] + red[3]);
    long long nv = (long long)BATCH * (nvr[0] + nvr[1] + nvr[2] + nvr[3]);
    __threadfence();
    unsigned int old = atomicAdd(ticket, 1u);
    if (old == POSFIN_BLOCKS - 1) {
      float total = atomicAdd(loss, 0.0f);   // device-scope read of final sum
      out[0] = (nv > 0) ? total / (float)nv : 0.0f;
    }
  }
}

// ---------------------------------------------------------------------------
// Launch. Workspace layout (~8.6 MB):
//   [0, 8388608)              xb: bf16 normalized feats
//   [8388608, +65536)         negsum: fp32 [B][S]   (plain-stored by sim)
//   [8454144, +4)             loss accumulator      (zeroed by k1)
//   [8454148, +4)             ticket                (zeroed by k1)
//   [8454208, +65504)         sp: fp32 [B][S-1]     (fully overwritten)
// ---------------------------------------------------------------------------
extern "C" void kernel_launch(void* const* d_in, const int* in_sizes, int n_in,
                              void* d_out, int out_size, void* d_ws, size_t ws_size,
                              hipStream_t stream) {
  const float* x = (const float*)d_in[0];
  unsigned short* xb = (unsigned short*)d_ws;
  const size_t XB_BYTES = (size_t)BATCH * SEQ * DIM * 2;   // 8388608
  const size_t NS_BYTES = (size_t)BATCH * SEQ * 4;         // 65536
  float* negsum        = (float*)((char*)d_ws + XB_BYTES);
  float* loss          = (float*)((char*)d_ws + XB_BYTES + NS_BYTES);
  unsigned int* ticket = (unsigned int*)((char*)d_ws + XB_BYTES + NS_BYTES + 4);
  float* sp            = (float*)((char*)d_ws + XB_BYTES + NS_BYTES + 64);

  normalize_bf16_kernel<<<(BATCH * SEQ) / 4, 256, 0, stream>>>(x, xb, negsum);

  sim_negsum_kernel<<<NSTRIP * BATCH, 512, 0, stream>>>(xb, negsum, sp);

  pos_fin_kernel<<<POSFIN_BLOCKS, 256, 0, stream>>>(sp, negsum, loss, ticket,
                                                    (float*)d_out);
}

// Round 8
// 85.705 us; speedup vs baseline: 1.0010x; 1.0010x over previous
//
#include <hip/hip_runtime.h>

// Problem constants (from reference: img_feats (8, 2048, 256) fp32)
#define BATCH 8
#define SEQ   2048
#define DIM   256
#define TINV  10.0f   // 1 / TEMPERATURE
#define NEGW  10      // NEG_WINDOW

#define BMROWS 64                 // rows per block
#define NSTRIP (SEQ / BMROWS)     // 32 strips
// grid = NSTRIP*BATCH = 256 blocks; blockIdx.x = strip*8 + batch so the
// natural %8 XCD round-robin keeps each batch's 1MB slice in one XCD L2
// (verified round 7: FETCH_SIZE 33MB -> 6.2MB).

typedef float f32x4  __attribute__((ext_vector_type(4)));
typedef short bf16x8 __attribute__((ext_vector_type(8)));

// float -> bf16 (round-to-nearest-even)
__device__ __forceinline__ unsigned short f2b(float f) {
  union { float f; unsigned u; } v; v.f = f;
  unsigned r = v.u + 0x7fffu + ((v.u >> 16) & 1u);
  return (unsigned short)(r >> 16);
}

// ---------------------------------------------------------------------------
// Kernel 1: L2-normalize rows (fp32 in) -> bf16 normalized rows in workspace.
// Block 64 also zero-inits the loss accumulator + ticket.
// ---------------------------------------------------------------------------
__global__ void normalize_bf16_kernel(const float* __restrict__ x,
                                      unsigned short* __restrict__ xb,
                                      float* __restrict__ zero_region) {
  if (blockIdx.x == 64 && threadIdx.x < 16) {
    zero_region[16384 + threadIdx.x] = 0.f;   // loss, ticket, pad
  }
  int row  = blockIdx.x * 4 + (threadIdx.x >> 6);
  int lane = threadIdx.x & 63;
  const float4 v = reinterpret_cast<const float4*>(x + (size_t)row * DIM)[lane];
  float ss = v.x * v.x + v.y * v.y + v.z * v.z + v.w * v.w;
#pragma unroll
  for (int off = 32; off; off >>= 1) ss += __shfl_xor(ss, off, 64);
  float rn = 1.0f / fmaxf(sqrtf(ss), 1e-12f);
  ushort4 o;
  o.x = f2b(v.x * rn); o.y = f2b(v.y * rn);
  o.z = f2b(v.z * rn); o.w = f2b(v.w * rn);
  reinterpret_cast<ushort4*>(xb + (size_t)row * DIM)[lane] = o;
}

// ---------------------------------------------------------------------------
// Kernel 2: one block per (batch, 64-row strip), 8 waves = 2 mw x 4 nw.
// A-frags live in registers (64 VGPR, loaded once); B streams through an
// explicit b0/b1 register double-buffer with static parity.
//
// ROUND-8 FIX: round 7 declared __launch_bounds__(512,2) -> compiler capped
// at 128 VGPRs while the kernel needs ~216 -> ~90 VGPRs spilled to scratch
// (evidence: WRITE_SIZE 4.7MB/dispatch vs ~130KB of real stores; all pipes
// idle). (512,1) -> one 8-wave block per CU, 2 waves/SIMD, 256-VGPR budget,
// zero spill. ILP (prefetch) + 2 waves/SIMD hide the L2 latency.
// ---------------------------------------------------------------------------
__global__ __launch_bounds__(512, 1)
void sim_negsum_kernel(const unsigned short* __restrict__ xb,
                       float* __restrict__ negsum,
                       float* __restrict__ sp_out) {
  const int batch = blockIdx.x & 7;
  const int strip = blockIdx.x >> 3;
  const int r0 = strip * BMROWS;

  const int tid  = threadIdx.x;
  const int wid  = tid >> 6;
  const int lane = tid & 63;
  const int mw   = wid >> 2;      // 0..1: rows r0+mw*32 .. +32
  const int nw   = wid & 3;       // 0..3: cols nw*512 .. +512
  const int kg   = lane >> 4;     // 0..3
  const int cl   = lane & 15;

  __shared__ float red[BMROWS];
  if (tid < BMROWS) red[tid] = 0.f;

  const unsigned short* Xb = xb + (size_t)batch * SEQ * DIM;

  // ---- A fragments in registers: rows r0+mw*32+m*16+cl, k = kc*32+kg*8 ----
  bf16x8 af[2][8];
  {
    const unsigned short* Ab = Xb + (size_t)(r0 + mw * 32 + cl) * DIM + kg * 8;
#pragma unroll
    for (int m = 0; m < 2; ++m)
#pragma unroll
      for (int kc = 0; kc < 8; ++kc)
        af[m][kc] = *reinterpret_cast<const bf16x8*>(Ab + m * 16 * DIM + kc * 32);
  }

  // per-lane B base: col nw*512+cl, k-offset kg*8
  const unsigned short* Bb = Xb + (size_t)(nw * 512 + cl) * DIM + kg * 8;

  float rowpart[2][4];
#pragma unroll
  for (int m = 0; m < 2; ++m)
#pragma unroll
    for (int r = 0; r < 4; ++r) rowpart[m][r] = 0.f;

  bf16x8 b0[8], b1[8];
  // preload (nb=0, kc=0) into b0
#pragma unroll
  for (int n = 0; n < 8; ++n)
    b0[n] = *reinterpret_cast<const bf16x8*>(Bb + (size_t)(n * 16) * DIM);

#define LOADB(dst, base)                                                      \
  _Pragma("unroll")                                                           \
  for (int n = 0; n < 8; ++n)                                                 \
    dst[n] = *reinterpret_cast<const bf16x8*>((base) + (size_t)(n * 16) * DIM);

#define MFMAB(cur, kc)                                                        \
  _Pragma("unroll")                                                           \
  for (int m = 0; m < 2; ++m)                                                 \
    _Pragma("unroll")                                                         \
    for (int n = 0; n < 8; ++n)                                               \
      acc[m][n] = __builtin_amdgcn_mfma_f32_16x16x32_bf16(                    \
          af[m][kc], cur[n], acc[m][n], 0, 0, 0);

  for (int nb = 0; nb < 4; ++nb) {
    const unsigned short* Bnb = Bb + (size_t)(nb * 128) * DIM;
    f32x4 acc[2][8];
#pragma unroll
    for (int m = 0; m < 2; ++m)
#pragma unroll
      for (int n = 0; n < 8; ++n)
        acc[m][n] = (f32x4){0.f, 0.f, 0.f, 0.f};

#pragma unroll
    for (int kc = 0; kc < 8; ++kc) {
      if ((kc & 1) == 0) {
        // prefetch next step into b1, consume b0
        LOADB(b1, Bnb + (kc + 1) * 32);
        MFMAB(b0, kc);
      } else if (kc < 7) {
        LOADB(b0, Bnb + (kc + 1) * 32);
        MFMAB(b1, kc);
      } else {
        // kc == 7: prefetch next nb's kc=0 into b0 (hidden under epilogue)
        if (nb < 3) { LOADB(b0, Bb + (size_t)((nb + 1) * 128) * DIM); }
        MFMAB(b1, kc);
      }
    }

    // ---- epilogue for this nb: exp + band mask + rowpart + sp ----
    // C/D layout (HW-verified): col = cl, row_in_tile = kg*4 + rr
#pragma unroll
    for (int m = 0; m < 2; ++m) {
      const int rowb = r0 + mw * 32 + m * 16 + (kg << 2);
#pragma unroll
      for (int n = 0; n < 8; ++n) {
        const int tcol = nw * 512 + nb * 128 + n * 16 + cl;
#pragma unroll
        for (int rr = 0; rr < 4; ++rr) {
          int srow = rowb + rr;
          int diff = tcol - srow;
          int d = diff < 0 ? -diff : diff;
          float sv = acc[m][n][rr] * TINV;
          float e = (d >= NEGW) ? __expf(sv) : 0.f;
          rowpart[m][rr] += e;
          if (diff == 1)   // positive pair (srow, srow+1): unique writer
            sp_out[(size_t)batch * (SEQ - 1) + srow] = sv;
        }
      }
    }
  }
#undef LOADB
#undef MFMAB

  // ---- reduce rowpart over the 16 cl-lanes of each kg group ----
#pragma unroll
  for (int off = 1; off <= 8; off <<= 1)
#pragma unroll
    for (int m = 0; m < 2; ++m)
#pragma unroll
      for (int r = 0; r < 4; ++r)
        rowpart[m][r] += __shfl_xor(rowpart[m][r], off, 64);

  __syncthreads();   // red[] init visible
  if (cl == 0) {
#pragma unroll
    for (int m = 0; m < 2; ++m)
#pragma unroll
      for (int r = 0; r < 4; ++r)
        atomicAdd(&red[mw * 32 + m * 16 + (kg << 2) + r], rowpart[m][r]);
  }
  __syncthreads();
  if (tid < BMROWS)
    negsum[(size_t)batch * SEQ + r0 + tid] = red[tid];
}

// ---------------------------------------------------------------------------
// Kernel 3: positive-pair loss from precomputed sp + FUSED finalize via
// last-block ticket. Every block computes n_valid redundantly; the block
// taking the last ticket reads the final loss and writes out.
// ---------------------------------------------------------------------------
__device__ __forceinline__ int negcnt(int s) {
  int a = s - (NEGW - 1);      if (a < 0) a = 0;
  int b = SEQ - NEGW - s;      if (b < 0) b = 0;
  return a + b;
}

#define POSFIN_BLOCKS 64

__global__ __launch_bounds__(256)
void pos_fin_kernel(const float* __restrict__ sp,
                    const float* __restrict__ negsum,
                    float* __restrict__ loss,
                    unsigned int* __restrict__ ticket,
                    float* __restrict__ out) {
  __shared__ float red[4];
  __shared__ int   nvr[4];
  const int NP = BATCH * (SEQ - 1);
  int pidx = blockIdx.x * 256 + threadIdx.x;
  float term = 0.f;
  if (pidx < NP) {
    int b = pidx / (SEQ - 1), s = pidx % (SEQ - 1);
    float spv = sp[pidx];
    float e = __expf(spv);
    if (negcnt(s) > 0)     term += logf(e + negsum[(size_t)b * SEQ + s])     - spv;
    if (negcnt(s + 1) > 0) term += logf(e + negsum[(size_t)b * SEQ + s + 1]) - spv;
  }
  // n_valid (per-anchor positive counts over valid anchors), generic form
  int cnt = 0;
#pragma unroll
  for (int s = threadIdx.x; s < SEQ; s += 256)
    if (negcnt(s) > 0) cnt += (s > 0) + (s < SEQ - 1);

#pragma unroll
  for (int off = 32; off; off >>= 1) {
    term += __shfl_xor(term, off, 64);
    cnt  += __shfl_xor(cnt,  off, 64);
  }
  if ((threadIdx.x & 63) == 0) {
    red[threadIdx.x >> 6] = term;
    nvr[threadIdx.x >> 6] = cnt;
  }
  __syncthreads();
  if (threadIdx.x == 0) {
    atomicAdd(loss, red[0] + red[1] + red[2] + red[3]);
    long long nv = (long long)BATCH * (nvr[0] + nvr[1] + nvr[2] + nvr[3]);
    __threadfence();
    unsigned int old = atomicAdd(ticket, 1u);
    if (old == POSFIN_BLOCKS - 1) {
      float total = atomicAdd(loss, 0.0f);   // device-scope read of final sum
      out[0] = (nv > 0) ? total / (float)nv : 0.0f;
    }
  }
}

// ---------------------------------------------------------------------------
// Launch. Workspace layout (~8.6 MB):
//   [0, 8388608)              xb: bf16 normalized feats
//   [8388608, +65536)         negsum: fp32 [B][S]   (plain-stored by sim)
//   [8454144, +4)             loss accumulator      (zeroed by k1)
//   [8454148, +4)             ticket                (zeroed by k1)
//   [8454208, +65504)         sp: fp32 [B][S-1]     (fully overwritten)
// ---------------------------------------------------------------------------
extern "C" void kernel_launch(void* const* d_in, const int* in_sizes, int n_in,
                              void* d_out, int out_size, void* d_ws, size_t ws_size,
                              hipStream_t stream) {
  const float* x = (const float*)d_in[0];
  unsigned short* xb = (unsigned short*)d_ws;
  const size_t XB_BYTES = (size_t)BATCH * SEQ * DIM * 2;   // 8388608
  const size_t NS_BYTES = (size_t)BATCH * SEQ * 4;         // 65536
  float* negsum        = (float*)((char*)d_ws + XB_BYTES);
  float* loss          = (float*)((char*)d_ws + XB_BYTES + NS_BYTES);
  unsigned int* ticket = (unsigned int*)((char*)d_ws + XB_BYTES + NS_BYTES + 4);
  float* sp            = (float*)((char*)d_ws + XB_BYTES + NS_BYTES + 64);

  normalize_bf16_kernel<<<(BATCH * SEQ) / 4, 256, 0, stream>>>(x, xb, negsum);

  sim_negsum_kernel<<<NSTRIP * BATCH, 512, 0, stream>>>(xb, negsum, sp);

  pos_fin_kernel<<<POSFIN_BLOCKS, 256, 0, stream>>>(sp, negsum, loss, ticket,
                                                    (float*)d_out);
}

// Round 9
// 64.896 us; speedup vs baseline: 1.3220x; 1.3206x over previous
//
#include <hip/hip_runtime.h>

// Problem constants (from reference: img_feats (8, 2048, 256) fp32)
#define BATCH 8
#define SEQ   2048
#define DIM   256
#define TINV  10.0f   // 1 / TEMPERATURE
#define NEGW  10      // NEG_WINDOW

// GEMM tiling (R6 structure: 128x128 tile pairs, ti<=tj symmetry)
#define BM 128
#define BN 128
#define NTILE (SEQ / BM)                  // 16
#define NPAIR (NTILE * (NTILE + 1) / 2)   // 136

typedef float f32x4  __attribute__((ext_vector_type(4)));
typedef short bf16x8 __attribute__((ext_vector_type(8)));

// float -> bf16 (round-to-nearest-even)
__device__ __forceinline__ unsigned short f2b(float f) {
  union { float f; unsigned u; } v; v.f = f;
  unsigned r = v.u + 0x7fffu + ((v.u >> 16) & 1u);
  return (unsigned short)(r >> 16);
}

// ---------------------------------------------------------------------------
// Kernel 1: L2-normalize rows (fp32 in) -> bf16 normalized rows in workspace.
// Blocks 0..63 zero negsum (sim uses atomics again); block 64 zeros loss+ticket.
// ---------------------------------------------------------------------------
__global__ void normalize_bf16_kernel(const float* __restrict__ x,
                                      unsigned short* __restrict__ xb,
                                      float* __restrict__ zero_region) {
  if (blockIdx.x < 64) {
    zero_region[blockIdx.x * 256 + threadIdx.x] = 0.f;   // negsum
  } else if (blockIdx.x == 64 && threadIdx.x < 16) {
    zero_region[16384 + threadIdx.x] = 0.f;              // loss, ticket, pad
  }
  int row  = blockIdx.x * 4 + (threadIdx.x >> 6);
  int lane = threadIdx.x & 63;
  const float4 v = reinterpret_cast<const float4*>(x + (size_t)row * DIM)[lane];
  float ss = v.x * v.x + v.y * v.y + v.z * v.z + v.w * v.w;
#pragma unroll
  for (int off = 32; off; off >>= 1) ss += __shfl_xor(ss, off, 64);
  float rn = 1.0f / fmaxf(sqrtf(ss), 1e-12f);
  ushort4 o;
  o.x = f2b(v.x * rn); o.y = f2b(v.y * rn);
  o.z = f2b(v.z * rn); o.w = f2b(v.w * rn);
  reinterpret_cast<ushort4*>(xb + (size_t)row * DIM)[lane] = o;
}

// ---------------------------------------------------------------------------
// Kernel 2 (round-9): R6's no-LDS 128x128 structure + EXPLICIT register
// double-buffer prefetch, sized to fit 3 waves/EU.
//   - R6 (72 VGPR, no lookahead): per kc-step {8 loads -> vmcnt(0) -> 16
//     MFMA} fully serialized -> 55us, everything idle.
//   - R7/R8 (8-wave block, ~220-reg set): allocator capped at 128, spilled.
//   - Now: af-dbuf 32 + bf-dbuf 32 + acc 64 (AGPRs, proven by R6's
//     VGPR=72) + ~20 misc ~= 150 regs <= 170 budget of launch_bounds(256,3)
//     -> 3 blocks/CU = 12 waves/CU, AND loads for kc+1 issue before the
//     MFMAs of kc (compiler emits counted vmcnt via register deps).
// Epilogue unchanged from R6 (verified absmax 0 four rounds running).
// ---------------------------------------------------------------------------
__global__ __launch_bounds__(256, 3)
void sim_negsum_kernel(const unsigned short* __restrict__ xb,
                       float* __restrict__ negsum,
                       float* __restrict__ sp_out) {
  const int b = blockIdx.y;
  int ti = 0, rem = blockIdx.x;
  while (rem >= NTILE - ti) { rem -= NTILE - ti; ti++; }
  const int tj = ti + rem;
  const bool diag = (ti == tj);
  const int s0 = ti * BM, t0 = tj * BN;

  const int tid  = threadIdx.x;
  const int wid  = tid >> 6;
  const int lane = tid & 63;
  const int wm   = wid >> 1;       // wave row strip (0..1)
  const int wn   = wid & 1;        // wave col strip (0..1)
  const int kg   = lane >> 4;      // k-group 0..3
  const int cl   = lane & 15;

  // per-lane fragment bases (16B loads; 64 lanes cover 16 rows x 64B = 1KB,
  // fully coalesced into 16 cachelines per instruction)
  const unsigned short* Abase =
      xb + (size_t)b * SEQ * DIM + (size_t)(s0 + wm * 64 + cl) * DIM + kg * 8;
  const unsigned short* Bbase =
      xb + (size_t)b * SEQ * DIM + (size_t)(t0 + wn * 64 + cl) * DIM + kg * 8;

  f32x4 acc[4][4];
#pragma unroll
  for (int m = 0; m < 4; ++m)
#pragma unroll
    for (int n = 0; n < 4; ++n)
      acc[m][n] = (f32x4){0.f, 0.f, 0.f, 0.f};

  bf16x8 pa0[4], pa1[4], pb0[4], pb1[4];

#define LOADF(dst, base, kc)                                                  \
  _Pragma("unroll")                                                           \
  for (int q = 0; q < 4; ++q)                                                 \
    dst[q] = *reinterpret_cast<const bf16x8*>(                                \
        (base) + (size_t)(q * 16) * DIM + (kc) * 32);

#define MFMAS(A, B)                                                           \
  _Pragma("unroll")                                                           \
  for (int m = 0; m < 4; ++m)                                                 \
    _Pragma("unroll")                                                         \
    for (int n = 0; n < 4; ++n)                                               \
      acc[m][n] = __builtin_amdgcn_mfma_f32_16x16x32_bf16(                    \
          A[m], B[n], acc[m][n], 0, 0, 0);

  LOADF(pa0, Abase, 0);
  LOADF(pb0, Bbase, 0);
#pragma unroll
  for (int kc = 0; kc < 8; ++kc) {   // 8 K-chunks of 32 (DIM=256)
    if ((kc & 1) == 0) {
      if (kc < 7) { LOADF(pa1, Abase, kc + 1); LOADF(pb1, Bbase, kc + 1); }
      MFMAS(pa0, pb0);
    } else {
      if (kc < 7) { LOADF(pa0, Abase, kc + 1); LOADF(pb0, Bbase, kc + 1); }
      MFMAS(pa1, pb1);
    }
  }
#undef LOADF
#undef MFMAS

  // ---- epilogue: exp + mask + row/col partial sums + sp extraction ----
  // C/D layout (HW-verified): col = lane&15, row = (lane>>4)*4 + reg
  float rowpart[4][4];
  float colpart[4];
#pragma unroll
  for (int m = 0; m < 4; ++m)
#pragma unroll
    for (int r = 0; r < 4; ++r) rowpart[m][r] = 0.f;
#pragma unroll
  for (int n = 0; n < 4; ++n) colpart[n] = 0.f;

#pragma unroll
  for (int m = 0; m < 4; ++m) {
#pragma unroll
    for (int n = 0; n < 4; ++n) {
#pragma unroll
      for (int r = 0; r < 4; ++r) {
        int srow = s0 + wm * 64 + m * 16 + (kg << 2) + r;
        int tcol = t0 + wn * 64 + n * 16 + cl;
        int diff = tcol - srow;
        int d = diff < 0 ? -diff : diff;
        float sv = acc[m][n][r] * TINV;
        float e = (d >= NEGW) ? __expf(sv) : 0.f;
        rowpart[m][r] += e;
        colpart[n]    += e;
        if (diff == 1)   // positive pair (srow, srow+1): unique writer
          sp_out[(size_t)b * (SEQ - 1) + srow] = sv;
      }
    }
  }

#pragma unroll
  for (int off = 1; off <= 8; off <<= 1)
#pragma unroll
    for (int m = 0; m < 4; ++m)
#pragma unroll
      for (int r = 0; r < 4; ++r)
        rowpart[m][r] += __shfl_xor(rowpart[m][r], off, 64);
  if (cl == 0) {
#pragma unroll
    for (int m = 0; m < 4; ++m)
#pragma unroll
      for (int r = 0; r < 4; ++r)
        atomicAdd(&negsum[(size_t)b * SEQ + s0 + wm * 64 + m * 16 + (kg << 2) + r],
                  rowpart[m][r]);
  }

  if (!diag) {
#pragma unroll
    for (int off = 16; off <= 32; off <<= 1)
#pragma unroll
      for (int n = 0; n < 4; ++n)
        colpart[n] += __shfl_xor(colpart[n], off, 64);
    if (lane < 16) {
#pragma unroll
      for (int n = 0; n < 4; ++n)
        atomicAdd(&negsum[(size_t)b * SEQ + t0 + wn * 64 + n * 16 + lane],
                  colpart[n]);
    }
  }
}

// ---------------------------------------------------------------------------
// Kernel 3: positive-pair loss from precomputed sp + FUSED finalize via
// last-block ticket.
// ---------------------------------------------------------------------------
__device__ __forceinline__ int negcnt(int s) {
  int a = s - (NEGW - 1);      if (a < 0) a = 0;
  int b = SEQ - NEGW - s;      if (b < 0) b = 0;
  return a + b;
}

#define POSFIN_BLOCKS 64

__global__ __launch_bounds__(256)
void pos_fin_kernel(const float* __restrict__ sp,
                    const float* __restrict__ negsum,
                    float* __restrict__ loss,
                    unsigned int* __restrict__ ticket,
                    float* __restrict__ out) {
  __shared__ float red[4];
  __shared__ int   nvr[4];
  const int NP = BATCH * (SEQ - 1);
  int pidx = blockIdx.x * 256 + threadIdx.x;
  float term = 0.f;
  if (pidx < NP) {
    int b = pidx / (SEQ - 1), s = pidx % (SEQ - 1);
    float spv = sp[pidx];
    float e = __expf(spv);
    if (negcnt(s) > 0)     term += logf(e + negsum[(size_t)b * SEQ + s])     - spv;
    if (negcnt(s + 1) > 0) term += logf(e + negsum[(size_t)b * SEQ + s + 1]) - spv;
  }
  int cnt = 0;
#pragma unroll
  for (int s = threadIdx.x; s < SEQ; s += 256)
    if (negcnt(s) > 0) cnt += (s > 0) + (s < SEQ - 1);

#pragma unroll
  for (int off = 32; off; off >>= 1) {
    term += __shfl_xor(term, off, 64);
    cnt  += __shfl_xor(cnt,  off, 64);
  }
  if ((threadIdx.x & 63) == 0) {
    red[threadIdx.x >> 6] = term;
    nvr[threadIdx.x >> 6] = cnt;
  }
  __syncthreads();
  if (threadIdx.x == 0) {
    atomicAdd(loss, red[0] + red[1] + red[2] + red[3]);
    long long nv = (long long)BATCH * (nvr[0] + nvr[1] + nvr[2] + nvr[3]);
    __threadfence();
    unsigned int old = atomicAdd(ticket, 1u);
    if (old == POSFIN_BLOCKS - 1) {
      float total = atomicAdd(loss, 0.0f);   // device-scope read of final sum
      out[0] = (nv > 0) ? total / (float)nv : 0.0f;
    }
  }
}

// ---------------------------------------------------------------------------
// Launch. Workspace layout (~8.6 MB):
//   [0, 8388608)              xb: bf16 normalized feats
//   [8388608, +65536)         negsum: fp32 [B][S]   (zeroed by k1)
//   [8454144, +4)             loss accumulator      (zeroed by k1)
//   [8454148, +4)             ticket                (zeroed by k1)
//   [8454208, +65504)         sp: fp32 [B][S-1]     (fully overwritten)
// ---------------------------------------------------------------------------
extern "C" void kernel_launch(void* const* d_in, const int* in_sizes, int n_in,
                              void* d_out, int out_size, void* d_ws, size_t ws_size,
                              hipStream_t stream) {
  const float* x = (const float*)d_in[0];
  unsigned short* xb = (unsigned short*)d_ws;
  const size_t XB_BYTES = (size_t)BATCH * SEQ * DIM * 2;   // 8388608
  const size_t NS_BYTES = (size_t)BATCH * SEQ * 4;         // 65536
  float* negsum        = (float*)((char*)d_ws + XB_BYTES);
  float* loss          = (float*)((char*)d_ws + XB_BYTES + NS_BYTES);
  unsigned int* ticket = (unsigned int*)((char*)d_ws + XB_BYTES + NS_BYTES + 4);
  float* sp            = (float*)((char*)d_ws + XB_BYTES + NS_BYTES + 64);

  normalize_bf16_kernel<<<(BATCH * SEQ) / 4, 256, 0, stream>>>(x, xb, negsum);

  dim3 g2(NPAIR, BATCH);
  sim_negsum_kernel<<<g2, 256, 0, stream>>>(xb, negsum, sp);

  pos_fin_kernel<<<POSFIN_BLOCKS, 256, 0, stream>>>(sp, negsum, loss, ticket,
                                                    (float*)d_out);
}